// Round 3
// baseline (322.390 us; speedup 1.0000x reference)
//
#include <hip/hip_runtime.h>
#include <hip/hip_bf16.h>

// N=4,B=8,T=2,E=1024,H=16,D=64,S=2048,L=1024
#define NB_  32
#define T_   2
#define E_   1024
#define H_   16
#define D_   64
#define S_   2048
#define L_   1024
#define TOT_ (S_ + L_ + T_)   // 3074
#define CHUNKS_ 4
#define CPOS_ (S_ / CHUNKS_)  // 512

#define LOG2E_ 1.4426950408889634f
#define QS_ (0.125f * LOG2E_)

// ---------------------------------------------------------------------------
// QKV: out[64][3072] = hidden[64][1024] @ Wcat^T + bias.
// 384 blocks x 256 thr (4 waves, 2 cols/wave -> 8 cols/block, 1536 waves).
// hidden chunk transposed in LDS (stride 65, conflict-free b32 reads).
// ---------------------------------------------------------------------------
__global__ __launch_bounds__(256) void qkv_kernel(
    const float* __restrict__ hidden,
    const float* __restrict__ Wq, const float* __restrict__ bq,
    const float* __restrict__ Wk, const float* __restrict__ bk,
    const float* __restrict__ Wv, const float* __restrict__ bv,
    float* __restrict__ qT,      // [1024][64]
    float* __restrict__ knew,    // [NB][H][T][D]
    float* __restrict__ vnew)
{
    __shared__ float ldsT[128 * 65];
    const int tid  = threadIdx.x;
    const int wave = tid >> 6;
    const int lane = tid & 63;          // token row r
    const int eg0  = blockIdx.x * 8;    // 8 cols per block
    const int mat  = eg0 >> 10;         // 0=q 1=k 2=v
    int e_in0 = (eg0 & 1023) + wave * 2;
    e_in0 = __builtin_amdgcn_readfirstlane(e_in0);

    const float* W    = (mat == 0) ? Wq : (mat == 1) ? Wk : Wv;
    const float* bias = (mat == 0) ? bq : (mat == 1) ? bk : bv;

    float acc0 = 0.f, acc1 = 0.f;

    for (int k0 = 0; k0 < 1024; k0 += 128) {
        __syncthreads();
        #pragma unroll
        for (int i = 0; i < 32; i++) {
            int f = i * 256 + tid;
            int r = f >> 7;
            int c = f & 127;
            ldsT[c * 65 + r] = hidden[r * 1024 + k0 + c];
        }
        __syncthreads();
        const float* w0 = W + (e_in0 + 0) * 1024 + k0;
        const float* w1 = W + (e_in0 + 1) * 1024 + k0;
        for (int kk = 0; kk < 128; kk += 4) {
            float h0 = ldsT[(kk + 0) * 65 + lane];
            float h1 = ldsT[(kk + 1) * 65 + lane];
            float h2 = ldsT[(kk + 2) * 65 + lane];
            float h3 = ldsT[(kk + 3) * 65 + lane];
            acc0 = fmaf(h0, w0[kk + 0], acc0);
            acc0 = fmaf(h1, w0[kk + 1], acc0);
            acc0 = fmaf(h2, w0[kk + 2], acc0);
            acc0 = fmaf(h3, w0[kk + 3], acc0);
            acc1 = fmaf(h0, w1[kk + 0], acc1);
            acc1 = fmaf(h1, w1[kk + 1], acc1);
            acc1 = fmaf(h2, w1[kk + 2], acc1);
            acc1 = fmaf(h3, w1[kk + 3], acc1);
        }
    }

    const int r = lane;
    #pragma unroll
    for (int j = 0; j < 2; j++) {
        int e_in = e_in0 + j;
        float val = (j == 0 ? acc0 : acc1) + bias[e_in];
        if (mat == 0) {
            qT[e_in * 64 + r] = val;
        } else {
            int nb = r >> 1, t = r & 1, h = e_in >> 6, d = e_in & 63;
            float* dst = (mat == 1) ? knew : vnew;
            dst[((nb * H_ + h) * T_ + t) * D_ + d] = val;
        }
    }
}

// ---------------------------------------------------------------------------
// Partial attention. grid = 768 x 256 threads.
//  blocks [0,512):   cur path, (nb,h): stream past_k/v (L) + new (T), 2 rows.
//  blocks [512,768): prefix path, (n,h,chunk): stream CPOS_ prefix positions,
//                    16 rows (8 beams x 2 t) per K-load. Lane=(r=lane&15,
//                    c=lane>>4): lane owns row r, dim quarter c (16 dims).
// Unnormalized (ctx,l) partials; combine kernel sums them (no-max exp2).
// ---------------------------------------------------------------------------
__global__ __launch_bounds__(256) void partial_kernel(
    const float* __restrict__ mask,   // [NB][TOT_]
    const float* __restrict__ pfx_k,  // [N][H][S][D]
    const float* __restrict__ pfx_v,
    const float* __restrict__ pk,     // [NB][H][L][D]
    const float* __restrict__ pv,
    const float* __restrict__ qT,     // [1024][64]
    const float* __restrict__ knew,   // [NB][H][T][D]
    const float* __restrict__ vnew,
    float* __restrict__ cur_ctx,      // [512][2][64]
    float* __restrict__ cur_l,        // [512][2]
    float* __restrict__ pfx_ctx,      // [N*H][CHUNKS_][16][64]
    float* __restrict__ pfx_l)        // [N*H][CHUNKS_][16]
{
    __shared__ float sred[4160];
    const int tid = threadIdx.x;

    if (blockIdx.x < 512) {
        // ----- cur path -----
        const int b  = blockIdx.x;
        const int nb = b >> 4;
        const int h  = b & 15;
        const int g   = tid >> 4;     // group 0..15
        const int l16 = tid & 15;
        const int d0  = l16 * 4;

        float qf0[4], qf1[4];
        #pragma unroll
        for (int j = 0; j < 4; j++) {
            const float* qb = qT + (h * 64 + d0 + j) * 64 + nb * 2;
            qf0[j] = qb[0] * QS_;
            qf1[j] = qb[1] * QS_;
        }

        const float* pk_b = pk + ((nb * H_ + h) * (size_t)L_) * D_;
        const float* pv_b = pv + ((nb * H_ + h) * (size_t)L_) * D_;
        const float* kn_b = knew + (nb * H_ + h) * (T_ * D_);
        const float* vn_b = vnew + (nb * H_ + h) * (T_ * D_);
        const float* mrow = mask + nb * TOT_ + S_;

        float l0 = 0.f, l1 = 0.f;
        float a0[4] = {0.f, 0.f, 0.f, 0.f};
        float a1[4] = {0.f, 0.f, 0.f, 0.f};

        for (int p = g; p < L_ + T_; p += 16) {
            const float* kp;
            const float* vp;
            if (p < L_) { kp = pk_b + p * D_;        vp = pv_b + p * D_; }
            else        { kp = kn_b + (p - L_) * D_; vp = vn_b + (p - L_) * D_; }

            float4 kf = *reinterpret_cast<const float4*>(kp + d0);
            float s0 = qf0[0] * kf.x + qf0[1] * kf.y + qf0[2] * kf.z + qf0[3] * kf.w;
            float s1 = qf1[0] * kf.x + qf1[1] * kf.y + qf1[2] * kf.z + qf1[3] * kf.w;
            #pragma unroll
            for (int off = 1; off < 16; off <<= 1) {
                s0 += __shfl_xor(s0, off, 64);
                s1 += __shfl_xor(s1, off, 64);
            }
            float mC = mrow[p] * LOG2E_;
            float e0 = exp2f(s0 + mC);
            float e1 = exp2f(s1 + mC);
            l0 += e0; l1 += e1;
            float4 vf = *reinterpret_cast<const float4*>(vp + d0);
            a0[0] += e0 * vf.x; a0[1] += e0 * vf.y; a0[2] += e0 * vf.z; a0[3] += e0 * vf.w;
            a1[0] += e1 * vf.x; a1[1] += e1 * vf.y; a1[2] += e1 * vf.z; a1[3] += e1 * vf.w;
        }

        #pragma unroll
        for (int j = 0; j < 4; j++) {
            sred[g * 128 + d0 + j]      = a0[j];
            sred[g * 128 + 64 + d0 + j] = a1[j];
        }
        if (l16 == 0) { sred[2048 + g * 2] = l0; sred[2048 + g * 2 + 1] = l1; }
        __syncthreads();

        if (tid < 128) {
            int t = tid >> 6, d = tid & 63;
            float s = 0.f, l = 0.f;
            for (int g2 = 0; g2 < 16; g2++) {
                s += sred[g2 * 128 + t * 64 + d];
                l += sred[2048 + g2 * 2 + t];
            }
            cur_ctx[(b * 2 + t) * 64 + d] = s;
            if (d == 0) cur_l[b * 2 + t] = l;
        }
    } else {
        // ----- prefix path -----
        const int idx   = blockIdx.x - 512;   // 0..255
        const int n     = idx >> 6;
        const int h     = (idx >> 2) & 15;
        const int chunk = idx & 3;
        const int wv    = tid >> 6;           // wave 0..3
        const int lane  = tid & 63;
        const int r     = lane & 15;          // row = beam*2 + t
        const int c     = lane >> 4;          // dim quarter

        float qreg[16];
        const float* qbase = qT + (h * 64 + c * 16) * 64 + (n * 16 + r);
        #pragma unroll
        for (int u = 0; u < 16; u++) qreg[u] = qbase[u * 64] * QS_;

        const size_t pos0 = (size_t)(n * H_ + h) * S_ + chunk * CPOS_;
        const float* kb = pfx_k + pos0 * D_ + c * 16;
        const float* vb = pfx_v + pos0 * D_ + c * 16;
        const float* mrow = mask + (n * 8 + (r >> 1)) * TOT_ + chunk * CPOS_;

        float ctx[16];
        #pragma unroll
        for (int u = 0; u < 16; u++) ctx[u] = 0.f;
        float lsum = 0.f;

        for (int i = 0; i < CPOS_ / 4; i++) {
            int p = i * 4 + wv;
            const float* kp = kb + p * D_;
            float4 k0 = *reinterpret_cast<const float4*>(kp + 0);
            float4 k1 = *reinterpret_cast<const float4*>(kp + 4);
            float4 k2 = *reinterpret_cast<const float4*>(kp + 8);
            float4 k3 = *reinterpret_cast<const float4*>(kp + 12);
            float s = qreg[0] * k0.x + qreg[1] * k0.y + qreg[2] * k0.z + qreg[3] * k0.w
                    + qreg[4] * k1.x + qreg[5] * k1.y + qreg[6] * k1.z + qreg[7] * k1.w
                    + qreg[8] * k2.x + qreg[9] * k2.y + qreg[10] * k2.z + qreg[11] * k2.w
                    + qreg[12] * k3.x + qreg[13] * k3.y + qreg[14] * k3.z + qreg[15] * k3.w;
            s += __shfl_xor(s, 16, 64);
            s += __shfl_xor(s, 32, 64);
            float e = exp2f(s + mrow[p] * LOG2E_);
            lsum += e;
            const float* vp = vb + p * D_;
            float4 v0 = *reinterpret_cast<const float4*>(vp + 0);
            float4 v1 = *reinterpret_cast<const float4*>(vp + 4);
            float4 v2 = *reinterpret_cast<const float4*>(vp + 8);
            float4 v3 = *reinterpret_cast<const float4*>(vp + 12);
            ctx[0]  += e * v0.x; ctx[1]  += e * v0.y; ctx[2]  += e * v0.z; ctx[3]  += e * v0.w;
            ctx[4]  += e * v1.x; ctx[5]  += e * v1.y; ctx[6]  += e * v1.z; ctx[7]  += e * v1.w;
            ctx[8]  += e * v2.x; ctx[9]  += e * v2.y; ctx[10] += e * v2.z; ctx[11] += e * v2.w;
            ctx[12] += e * v3.x; ctx[13] += e * v3.y; ctx[14] += e * v3.z; ctx[15] += e * v3.w;
        }

        const int base = wv * 1024 + r * 64 + c * 16;
        #pragma unroll
        for (int u = 0; u < 16; u += 4)
            *reinterpret_cast<float4*>(&sred[base + u]) =
                make_float4(ctx[u], ctx[u+1], ctx[u+2], ctx[u+3]);
        if (c == 0) sred[4096 + wv * 16 + r] = lsum;
        __syncthreads();

        const int pc = (n * H_ + h) * CHUNKS_ + chunk;
        for (int e = tid; e < 1024; e += 256) {
            float s = sred[e] + sred[1024 + e] + sred[2048 + e] + sred[3072 + e];
            pfx_ctx[pc * 1024 + e] = s;   // [pc][r][d], e = r*64+d
        }
        if (tid < 16) {
            float l = sred[4096 + tid] + sred[4096 + 16 + tid]
                    + sred[4096 + 32 + tid] + sred[4096 + 48 + tid];
            pfx_l[pc * 16 + tid] = l;
        }
    }
}

// ---------------------------------------------------------------------------
// Combine: out[nb*2+t][h*64+d] = (cur_ctx + sum_chunk pfx_ctx) / (cur_l + sum pfx_l)
// ---------------------------------------------------------------------------
__global__ __launch_bounds__(1024) void combine_kernel(
    const float* __restrict__ cur_ctx, const float* __restrict__ cur_l,
    const float* __restrict__ pfx_ctx, const float* __restrict__ pfx_l,
    float* __restrict__ out)
{
    const int row = blockIdx.x;           // nb*2+t
    const int nb  = row >> 1, t = row & 1;
    const int n   = nb >> 3, bp = nb & 7;
    const int r   = bp * 2 + t;
    const int tid = threadIdx.x;          // h*64+d
    const int h   = tid >> 6, d = tid & 63;
    const int b   = nb * 16 + h;

    float val = cur_ctx[(b * 2 + t) * 64 + d];
    float l   = cur_l[b * 2 + t];
    #pragma unroll
    for (int ch = 0; ch < CHUNKS_; ch++) {
        int pc = (n * H_ + h) * CHUNKS_ + ch;
        val += pfx_ctx[pc * 1024 + r * 64 + d];
        l   += pfx_l[pc * 16 + r];
    }
    out[row * 1024 + tid] = val / l;
}

extern "C" void kernel_launch(void* const* d_in, const int* in_sizes, int n_in,
                              void* d_out, int out_size, void* d_ws, size_t ws_size,
                              hipStream_t stream) {
    const float* hidden = (const float*)d_in[0];
    const float* mask   = (const float*)d_in[1];
    const float* pfxk   = (const float*)d_in[2];
    const float* pfxv   = (const float*)d_in[3];
    const float* pk     = (const float*)d_in[4];
    const float* pv     = (const float*)d_in[5];
    const float* Wq     = (const float*)d_in[6];
    const float* bq     = (const float*)d_in[7];
    const float* Wk     = (const float*)d_in[8];
    const float* bk     = (const float*)d_in[9];
    const float* Wv     = (const float*)d_in[10];
    const float* bv     = (const float*)d_in[11];

    float* qT      = (float*)d_ws;           // 65536
    float* knew    = qT + 65536;             // 65536
    float* vnew    = knew + 65536;           // 65536
    float* cur_ctx = vnew + 65536;           // 65536
    float* cur_l   = cur_ctx + 65536;        // 1024
    float* pfx_ctx = cur_l + 1024;           // 64*4*1024 = 262144
    float* pfx_l   = pfx_ctx + 262144;       // 4096

    qkv_kernel<<<384, 256, 0, stream>>>(hidden, Wq, bq, Wk, bk, Wv, bv,
                                        qT, knew, vnew);
    partial_kernel<<<768, 256, 0, stream>>>(mask, pfxk, pfxv, pk, pv,
                                            qT, knew, vnew,
                                            cur_ctx, cur_l, pfx_ctx, pfx_l);
    combine_kernel<<<64, 1024, 0, stream>>>(cur_ctx, cur_l, pfx_ctx, pfx_l,
                                            (float*)d_out);
}

// Round 4
// 213.923 us; speedup vs baseline: 1.5070x; 1.5070x over previous
//
#include <hip/hip_runtime.h>
#include <hip/hip_bf16.h>

// N=4,B=8,T=2,E=1024,H=16,D=64,S=2048,L=1024
#define NB_  32
#define T_   2
#define E_   1024
#define H_   16
#define D_   64
#define S_   2048
#define L_   1024
#define TOT_ (S_ + L_ + T_)   // 3074

#define PCH_  16              // prefix chunks  (128 pos each)
#define PLEN_ (S_ / PCH_)     // 128
#define CCH_  8               // cur chunks     (128 pos each; last gets +2)
#define CLEN_ (L_ / CCH_)     // 128

#define PFXBLK_ (4 * H_ * PCH_)   // 1024 prefix blocks
#define CURBLK_ (NB_ * H_ * CCH_) // 4096 cur blocks

#define LOG2E_ 1.4426950408889634f
#define QS_ (0.125f * LOG2E_)

// ---------------------------------------------------------------------------
// QKV: out[64][3072] = hidden[64][1024] @ Wcat^T + bias.
// 384 blocks x 256 thr, 2 cols/wave; 4 independent accumulators per column
// (breaks the 1024-long dependent fmaf chain -> 8 chains/wave).
// ---------------------------------------------------------------------------
__global__ __launch_bounds__(256) void qkv_kernel(
    const float* __restrict__ hidden,
    const float* __restrict__ Wq, const float* __restrict__ bq,
    const float* __restrict__ Wk, const float* __restrict__ bk,
    const float* __restrict__ Wv, const float* __restrict__ bv,
    float* __restrict__ qT,      // [1024][64]
    float* __restrict__ knew,    // [NB][H][T][D]
    float* __restrict__ vnew)
{
    __shared__ float ldsT[128 * 65];
    const int tid  = threadIdx.x;
    const int wave = tid >> 6;
    const int lane = tid & 63;          // token row r
    const int eg0  = blockIdx.x * 8;
    const int mat  = eg0 >> 10;         // 0=q 1=k 2=v
    int e_in0 = (eg0 & 1023) + wave * 2;
    e_in0 = __builtin_amdgcn_readfirstlane(e_in0);

    const float* W    = (mat == 0) ? Wq : (mat == 1) ? Wk : Wv;
    const float* bias = (mat == 0) ? bq : (mat == 1) ? bk : bv;

    float a0[4] = {0.f,0.f,0.f,0.f};
    float a1[4] = {0.f,0.f,0.f,0.f};

    for (int k0 = 0; k0 < 1024; k0 += 128) {
        __syncthreads();
        #pragma unroll
        for (int i = 0; i < 32; i++) {
            int f = i * 256 + tid;
            int r = f >> 7;
            int c = f & 127;
            ldsT[c * 65 + r] = hidden[r * 1024 + k0 + c];
        }
        __syncthreads();
        const float* w0 = W + (e_in0 + 0) * 1024 + k0;
        const float* w1 = W + (e_in0 + 1) * 1024 + k0;
        for (int kk = 0; kk < 128; kk += 4) {
            float h0 = ldsT[(kk + 0) * 65 + lane];
            float h1 = ldsT[(kk + 1) * 65 + lane];
            float h2 = ldsT[(kk + 2) * 65 + lane];
            float h3 = ldsT[(kk + 3) * 65 + lane];
            a0[0] = fmaf(h0, w0[kk + 0], a0[0]);
            a0[1] = fmaf(h1, w0[kk + 1], a0[1]);
            a0[2] = fmaf(h2, w0[kk + 2], a0[2]);
            a0[3] = fmaf(h3, w0[kk + 3], a0[3]);
            a1[0] = fmaf(h0, w1[kk + 0], a1[0]);
            a1[1] = fmaf(h1, w1[kk + 1], a1[1]);
            a1[2] = fmaf(h2, w1[kk + 2], a1[2]);
            a1[3] = fmaf(h3, w1[kk + 3], a1[3]);
        }
    }

    const int r = lane;
    #pragma unroll
    for (int j = 0; j < 2; j++) {
        int e_in = e_in0 + j;
        float* ac = (j == 0) ? a0 : a1;
        float val = ((ac[0] + ac[1]) + (ac[2] + ac[3])) + bias[e_in];
        if (mat == 0) {
            qT[e_in * 64 + r] = val;
        } else {
            int nb = r >> 1, t = r & 1, h = e_in >> 6, d = e_in & 63;
            float* dst = (mat == 1) ? knew : vnew;
            dst[((nb * H_ + h) * T_ + t) * D_ + d] = val;
        }
    }
}

// ---------------------------------------------------------------------------
// Partial attention. grid = PFXBLK_ + CURBLK_ = 5120 blocks x 256 thr.
//  [0, 1024):      prefix path (n,h,chunk16): 128 positions, 16 rows/load.
//  [1024, 5120):   cur path (nb,h,chunk8): 128 positions (+2 new on last).
// Unnormalized (ctx,l) partials; no-max exp2 softmax so partials add.
// ---------------------------------------------------------------------------
__global__ __launch_bounds__(256) void partial_kernel(
    const float* __restrict__ mask,   // [NB][TOT_]
    const float* __restrict__ pfx_k,  // [N][H][S][D]
    const float* __restrict__ pfx_v,
    const float* __restrict__ pk,     // [NB][H][L][D]
    const float* __restrict__ pv,
    const float* __restrict__ qT,     // [1024][64]
    const float* __restrict__ knew,   // [NB][H][T][D]
    const float* __restrict__ vnew,
    float* __restrict__ cur_ctx,      // [CURBLK_][2][64]
    float* __restrict__ cur_l,        // [CURBLK_][2]
    float* __restrict__ pfx_ctx,      // [N*H*PCH_][16][64]
    float* __restrict__ pfx_l)        // [N*H*PCH_][16]
{
    __shared__ float sred[4160];
    const int tid = threadIdx.x;

    if (blockIdx.x < PFXBLK_) {
        // ----- prefix path: 16 q-rows amortize each K/V load -----
        const int idx   = blockIdx.x;
        const int n     = idx >> 8;           // /(H_*PCH_)
        const int h     = (idx >> 4) & 15;
        const int chunk = idx & 15;
        const int wv    = tid >> 6;           // wave 0..3
        const int lane  = tid & 63;
        const int r     = lane & 15;          // row = beam*2 + t
        const int c     = lane >> 4;          // dim quarter

        float qreg[16];
        const float* qbase = qT + (h * 64 + c * 16) * 64 + (n * 16 + r);
        #pragma unroll
        for (int u = 0; u < 16; u++) qreg[u] = qbase[u * 64] * QS_;

        const size_t pos0 = (size_t)(n * H_ + h) * S_ + chunk * PLEN_;
        const float* kb = pfx_k + pos0 * D_ + c * 16;
        const float* vb = pfx_v + pos0 * D_ + c * 16;
        const float* mrow = mask + (n * 8 + (r >> 1)) * TOT_ + chunk * PLEN_;

        float ctx[16];
        #pragma unroll
        for (int u = 0; u < 16; u++) ctx[u] = 0.f;
        float lsum = 0.f;

        #pragma unroll 2
        for (int i = 0; i < PLEN_ / 4; i++) {
            int p = i * 4 + wv;
            const float* kp = kb + p * D_;
            float4 k0 = *reinterpret_cast<const float4*>(kp + 0);
            float4 k1 = *reinterpret_cast<const float4*>(kp + 4);
            float4 k2 = *reinterpret_cast<const float4*>(kp + 8);
            float4 k3 = *reinterpret_cast<const float4*>(kp + 12);
            // 4 independent 4-FMA sub-chains, tree-combined
            float sA = qreg[0]*k0.x;  sA = fmaf(qreg[1],k0.y,sA);
            sA = fmaf(qreg[2],k0.z,sA); sA = fmaf(qreg[3],k0.w,sA);
            float sB = qreg[4]*k1.x;  sB = fmaf(qreg[5],k1.y,sB);
            sB = fmaf(qreg[6],k1.z,sB); sB = fmaf(qreg[7],k1.w,sB);
            float sC = qreg[8]*k2.x;  sC = fmaf(qreg[9],k2.y,sC);
            sC = fmaf(qreg[10],k2.z,sC); sC = fmaf(qreg[11],k2.w,sC);
            float sD = qreg[12]*k3.x; sD = fmaf(qreg[13],k3.y,sD);
            sD = fmaf(qreg[14],k3.z,sD); sD = fmaf(qreg[15],k3.w,sD);
            float s = (sA + sB) + (sC + sD);
            s += __shfl_xor(s, 16, 64);
            s += __shfl_xor(s, 32, 64);
            float e = exp2f(s + mrow[p] * LOG2E_);
            lsum += e;
            const float* vp = vb + p * D_;
            float4 v0 = *reinterpret_cast<const float4*>(vp + 0);
            float4 v1 = *reinterpret_cast<const float4*>(vp + 4);
            float4 v2 = *reinterpret_cast<const float4*>(vp + 8);
            float4 v3 = *reinterpret_cast<const float4*>(vp + 12);
            ctx[0]  += e * v0.x; ctx[1]  += e * v0.y; ctx[2]  += e * v0.z; ctx[3]  += e * v0.w;
            ctx[4]  += e * v1.x; ctx[5]  += e * v1.y; ctx[6]  += e * v1.z; ctx[7]  += e * v1.w;
            ctx[8]  += e * v2.x; ctx[9]  += e * v2.y; ctx[10] += e * v2.z; ctx[11] += e * v2.w;
            ctx[12] += e * v3.x; ctx[13] += e * v3.y; ctx[14] += e * v3.z; ctx[15] += e * v3.w;
        }

        const int base = wv * 1024 + r * 64 + c * 16;
        #pragma unroll
        for (int u = 0; u < 16; u += 4)
            *reinterpret_cast<float4*>(&sred[base + u]) =
                make_float4(ctx[u], ctx[u+1], ctx[u+2], ctx[u+3]);
        if (c == 0) sred[4096 + wv * 16 + r] = lsum;
        __syncthreads();

        const int pc = (n * H_ + h) * PCH_ + chunk;
        for (int e = tid; e < 1024; e += 256) {
            float s = sred[e] + sred[1024 + e] + sred[2048 + e] + sred[3072 + e];
            pfx_ctx[pc * 1024 + e] = s;   // e = r*64 + d
        }
        if (tid < 16) {
            float l = sred[4096 + tid] + sred[4096 + 16 + tid]
                    + sred[4096 + 32 + tid] + sred[4096 + 48 + tid];
            pfx_l[pc * 16 + tid] = l;
        }
    } else {
        // ----- cur path -----
        const int idx   = blockIdx.x - PFXBLK_;   // 0..4095
        const int b     = idx >> 3;               // nb*16+h
        const int chunk = idx & 7;
        const int nb    = b >> 4;
        const int h     = b & 15;
        const int g     = tid >> 4;     // group 0..15
        const int l16   = tid & 15;
        const int d0    = l16 * 4;

        float qf0[4], qf1[4];
        #pragma unroll
        for (int j = 0; j < 4; j++) {
            const float* qb = qT + (h * 64 + d0 + j) * 64 + nb * 2;
            qf0[j] = qb[0] * QS_;
            qf1[j] = qb[1] * QS_;
        }

        const float* pk_b = pk + ((nb * H_ + h) * (size_t)L_) * D_;
        const float* pv_b = pv + ((nb * H_ + h) * (size_t)L_) * D_;
        const float* mrow = mask + nb * TOT_ + S_;

        float l0 = 0.f, l1 = 0.f;
        float a0[4] = {0.f,0.f,0.f,0.f};
        float a1[4] = {0.f,0.f,0.f,0.f};

        const int p0 = chunk * CLEN_ + g;
        #pragma unroll 2
        for (int i = 0; i < CLEN_ / 16; i++) {
            int p = p0 + i * 16;                  // always < L_
            float4 kf = *reinterpret_cast<const float4*>(pk_b + p * D_ + d0);
            float s0 = fmaf(qf0[0],kf.x, qf0[1]*kf.y) + fmaf(qf0[2],kf.z, qf0[3]*kf.w);
            float s1 = fmaf(qf1[0],kf.x, qf1[1]*kf.y) + fmaf(qf1[2],kf.z, qf1[3]*kf.w);
            #pragma unroll
            for (int off = 1; off < 16; off <<= 1) {
                s0 += __shfl_xor(s0, off, 64);
                s1 += __shfl_xor(s1, off, 64);
            }
            float mC = mrow[p] * LOG2E_;
            float e0 = exp2f(s0 + mC);
            float e1 = exp2f(s1 + mC);
            l0 += e0; l1 += e1;
            float4 vf = *reinterpret_cast<const float4*>(pv_b + p * D_ + d0);
            a0[0] += e0 * vf.x; a0[1] += e0 * vf.y; a0[2] += e0 * vf.z; a0[3] += e0 * vf.w;
            a1[0] += e1 * vf.x; a1[1] += e1 * vf.y; a1[2] += e1 * vf.z; a1[3] += e1 * vf.w;
        }
        if (chunk == 7 && g < 2) {                // 2 new tokens
            const float* kn_b = knew + (nb * H_ + h) * (T_ * D_);
            const float* vn_b = vnew + (nb * H_ + h) * (T_ * D_);
            float4 kf = *reinterpret_cast<const float4*>(kn_b + g * D_ + d0);
            float s0 = fmaf(qf0[0],kf.x, qf0[1]*kf.y) + fmaf(qf0[2],kf.z, qf0[3]*kf.w);
            float s1 = fmaf(qf1[0],kf.x, qf1[1]*kf.y) + fmaf(qf1[2],kf.z, qf1[3]*kf.w);
            #pragma unroll
            for (int off = 1; off < 16; off <<= 1) {
                s0 += __shfl_xor(s0, off, 64);
                s1 += __shfl_xor(s1, off, 64);
            }
            float mC = mrow[L_ + g] * LOG2E_;
            float e0 = exp2f(s0 + mC);
            float e1 = exp2f(s1 + mC);
            l0 += e0; l1 += e1;
            float4 vf = *reinterpret_cast<const float4*>(vn_b + g * D_ + d0);
            a0[0] += e0 * vf.x; a0[1] += e0 * vf.y; a0[2] += e0 * vf.z; a0[3] += e0 * vf.w;
            a1[0] += e1 * vf.x; a1[1] += e1 * vf.y; a1[2] += e1 * vf.z; a1[3] += e1 * vf.w;
        }

        #pragma unroll
        for (int j = 0; j < 4; j++) {
            sred[g * 128 + d0 + j]      = a0[j];
            sred[g * 128 + 64 + d0 + j] = a1[j];
        }
        if (l16 == 0) { sred[2048 + g * 2] = l0; sred[2048 + g * 2 + 1] = l1; }
        __syncthreads();

        if (tid < 128) {
            int t = tid >> 6, d = tid & 63;
            float s = 0.f, l = 0.f;
            for (int g2 = 0; g2 < 16; g2++) {
                s += sred[g2 * 128 + t * 64 + d];
                l += sred[2048 + g2 * 2 + t];
            }
            const int cb = b * CCH_ + chunk;
            cur_ctx[(cb * 2 + t) * 64 + d] = s;
            if (d == 0) cur_l[cb * 2 + t] = l;
        }
    }
}

// ---------------------------------------------------------------------------
// Combine: out = (sum of 8 cur + 16 prefix ctx partials) / (sum of l partials)
// ---------------------------------------------------------------------------
__global__ __launch_bounds__(1024) void combine_kernel(
    const float* __restrict__ cur_ctx, const float* __restrict__ cur_l,
    const float* __restrict__ pfx_ctx, const float* __restrict__ pfx_l,
    float* __restrict__ out)
{
    const int row = blockIdx.x;           // nb*2+t
    const int nb  = row >> 1, t = row & 1;
    const int n   = nb >> 3;
    const int r   = (nb & 7) * 2 + t;
    const int tid = threadIdx.x;          // h*64+d
    const int h   = tid >> 6, d = tid & 63;
    const int b   = nb * 16 + h;

    float val = 0.f, l = 0.f;
    #pragma unroll
    for (int ch = 0; ch < CCH_; ch++) {
        int cb = b * CCH_ + ch;
        val += cur_ctx[(cb * 2 + t) * 64 + d];
        l   += cur_l[cb * 2 + t];
    }
    #pragma unroll
    for (int ch = 0; ch < PCH_; ch++) {
        int pc = (n * H_ + h) * PCH_ + ch;
        val += pfx_ctx[pc * 1024 + r * 64 + d];
        l   += pfx_l[pc * 16 + r];
    }
    out[row * 1024 + tid] = val / l;
}

extern "C" void kernel_launch(void* const* d_in, const int* in_sizes, int n_in,
                              void* d_out, int out_size, void* d_ws, size_t ws_size,
                              hipStream_t stream) {
    const float* hidden = (const float*)d_in[0];
    const float* mask   = (const float*)d_in[1];
    const float* pfxk   = (const float*)d_in[2];
    const float* pfxv   = (const float*)d_in[3];
    const float* pk     = (const float*)d_in[4];
    const float* pv     = (const float*)d_in[5];
    const float* Wq     = (const float*)d_in[6];
    const float* bq     = (const float*)d_in[7];
    const float* Wk     = (const float*)d_in[8];
    const float* bk     = (const float*)d_in[9];
    const float* Wv     = (const float*)d_in[10];
    const float* bv     = (const float*)d_in[11];

    float* qT      = (float*)d_ws;             // 65536
    float* knew    = qT + 65536;               // 65536
    float* vnew    = knew + 65536;             // 65536
    float* cur_ctx = vnew + 65536;             // 4096*2*64 = 524288
    float* cur_l   = cur_ctx + 524288;         // 8192
    float* pfx_ctx = cur_l + 8192;             // 1024*1024 = 1048576
    float* pfx_l   = pfx_ctx + 1048576;        // 16384

    qkv_kernel<<<384, 256, 0, stream>>>(hidden, Wq, bq, Wk, bk, Wv, bv,
                                        qT, knew, vnew);
    partial_kernel<<<PFXBLK_ + CURBLK_, 256, 0, stream>>>(
        mask, pfxk, pfxv, pk, pv, qT, knew, vnew,
        cur_ctx, cur_l, pfx_ctx, pfx_l);
    combine_kernel<<<64, 1024, 0, stream>>>(cur_ctx, cur_l, pfx_ctx, pfx_l,
                                            (float*)d_out);
}

// Round 5
// 128.596 us; speedup vs baseline: 2.5070x; 1.6635x over previous
//
#include <hip/hip_runtime.h>
#include <hip/hip_bf16.h>

// N=4,B=8,T=2,E=1024,H=16,D=64,S=2048,L=1024
#define NB_  32
#define T_   2
#define E_   1024
#define H_   16
#define D_   64
#define S_   2048
#define L_   1024
#define TOT_ (S_ + L_ + T_)   // 3074

#define PCH_  16              // prefix chunks  (128 pos each)
#define PLEN_ (S_ / PCH_)     // 128
#define CCH_  8               // cur chunks     (128 pos each; last gets +2)
#define CLEN_ (L_ / CCH_)     // 128

#define PFXBLK_ (4 * H_ * PCH_)   // 1024 prefix blocks
#define CURBLK_ (NB_ * H_ * CCH_) // 4096 cur blocks

#define LOG2E_ 1.4426950408889634f
#define QS_ (0.125f * LOG2E_)

// ---------------------------------------------------------------------------
// QKV: out[64][3072] = hidden[64][1024] @ Wcat^T + bias.
// 192 blocks x 256 thr; 16 cols/block (4 cols/wave). BOTH operands staged in
// LDS: hidden transposed (stride 65, conflict-free b32), W rows via coalesced
// float4 global->LDS then wave-uniform float4 broadcast reads. No global
// loads in the FMA loop -> latency fully hidden by LDS pipelining.
// ---------------------------------------------------------------------------
__global__ __launch_bounds__(256) void qkv_kernel(
    const float* __restrict__ hidden,
    const float* __restrict__ Wq, const float* __restrict__ bq,
    const float* __restrict__ Wk, const float* __restrict__ bk,
    const float* __restrict__ Wv, const float* __restrict__ bv,
    float* __restrict__ qT,      // [1024][64]
    float* __restrict__ knew,    // [NB][H][T][D]
    float* __restrict__ vnew)
{
    __shared__ float ldsT[128 * 65];   // hidden chunk, transposed
    __shared__ float wlds[16 * 128];   // 16 W rows x 128 k
    const int tid  = threadIdx.x;
    const int wave = tid >> 6;
    const int lane = tid & 63;          // token row r
    const int eg0  = blockIdx.x * 16;
    const int mat  = eg0 >> 10;         // 0=q 1=k 2=v
    const int e0   = eg0 & 1023;        // col base within matrix
    int c0 = wave * 4;                  // block-local col base for this wave
    c0 = __builtin_amdgcn_readfirstlane(c0);

    const float* W    = (mat == 0) ? Wq : (mat == 1) ? Wk : Wv;
    const float* bias = (mat == 0) ? bq : (mat == 1) ? bk : bv;

    float acc[4] = {0.f, 0.f, 0.f, 0.f};

    for (int k0 = 0; k0 < 1024; k0 += 128) {
        __syncthreads();
        // stage hidden[0:64][k0:k0+128] transposed: ldsT[c][r]
        #pragma unroll
        for (int i = 0; i < 32; i++) {
            int f = i * 256 + tid;
            int r = f >> 7;
            int c = f & 127;
            ldsT[c * 65 + r] = hidden[r * 1024 + k0 + c];
        }
        // stage W[e0:e0+16][k0:k0+128]: coalesced float4 per lane
        #pragma unroll
        for (int i = 0; i < 2; i++) {
            int wr = (tid >> 5) + i * 8;     // 0..15
            int wc = (tid & 31) * 4;         // 0..124
            *reinterpret_cast<float4*>(&wlds[wr * 128 + wc]) =
                *reinterpret_cast<const float4*>(&W[(size_t)(e0 + wr) * 1024 + k0 + wc]);
        }
        __syncthreads();

        for (int kk = 0; kk < 128; kk += 4) {
            float h0 = ldsT[(kk + 0) * 65 + lane];
            float h1 = ldsT[(kk + 1) * 65 + lane];
            float h2 = ldsT[(kk + 2) * 65 + lane];
            float h3 = ldsT[(kk + 3) * 65 + lane];
            float4 w0 = *reinterpret_cast<const float4*>(&wlds[(c0 + 0) * 128 + kk]);
            float4 w1 = *reinterpret_cast<const float4*>(&wlds[(c0 + 1) * 128 + kk]);
            float4 w2 = *reinterpret_cast<const float4*>(&wlds[(c0 + 2) * 128 + kk]);
            float4 w3 = *reinterpret_cast<const float4*>(&wlds[(c0 + 3) * 128 + kk]);
            acc[0] = fmaf(h0, w0.x, acc[0]); acc[0] = fmaf(h1, w0.y, acc[0]);
            acc[0] = fmaf(h2, w0.z, acc[0]); acc[0] = fmaf(h3, w0.w, acc[0]);
            acc[1] = fmaf(h0, w1.x, acc[1]); acc[1] = fmaf(h1, w1.y, acc[1]);
            acc[1] = fmaf(h2, w1.z, acc[1]); acc[1] = fmaf(h3, w1.w, acc[1]);
            acc[2] = fmaf(h0, w2.x, acc[2]); acc[2] = fmaf(h1, w2.y, acc[2]);
            acc[2] = fmaf(h2, w2.z, acc[2]); acc[2] = fmaf(h3, w2.w, acc[2]);
            acc[3] = fmaf(h0, w3.x, acc[3]); acc[3] = fmaf(h1, w3.y, acc[3]);
            acc[3] = fmaf(h2, w3.z, acc[3]); acc[3] = fmaf(h3, w3.w, acc[3]);
        }
    }

    const int r = lane;
    #pragma unroll
    for (int j = 0; j < 4; j++) {
        int e_in = e0 + c0 + j;
        float val = acc[j] + bias[e_in];
        if (mat == 0) {
            qT[e_in * 64 + r] = val;                       // coalesced
        } else {
            int nb = r >> 1, t = r & 1, h = e_in >> 6, d = e_in & 63;
            float* dst = (mat == 1) ? knew : vnew;
            dst[((nb * H_ + h) * T_ + t) * D_ + d] = val;  // scatter, tiny
        }
    }
}

// ---------------------------------------------------------------------------
// Partial attention. grid = PFXBLK_ + CURBLK_ = 5120 blocks x 256 thr.
//  [0, 1024):      prefix path (n,h,chunk16): 128 positions, 16 rows/load.
//  [1024, 5120):   cur path (nb,h,chunk8): 128 positions (+2 new on last).
// Unnormalized (ctx,l) partials; no-max exp2 softmax so partials add.
// ---------------------------------------------------------------------------
__global__ __launch_bounds__(256) void partial_kernel(
    const float* __restrict__ mask,   // [NB][TOT_]
    const float* __restrict__ pfx_k,  // [N][H][S][D]
    const float* __restrict__ pfx_v,
    const float* __restrict__ pk,     // [NB][H][L][D]
    const float* __restrict__ pv,
    const float* __restrict__ qT,     // [1024][64]
    const float* __restrict__ knew,   // [NB][H][T][D]
    const float* __restrict__ vnew,
    float* __restrict__ cur_ctx,      // [CURBLK_][2][64]
    float* __restrict__ cur_l,        // [CURBLK_][2]
    float* __restrict__ pfx_ctx,      // [N*H*PCH_][16][64]
    float* __restrict__ pfx_l)        // [N*H*PCH_][16]
{
    __shared__ float sred[4160];
    const int tid = threadIdx.x;

    if (blockIdx.x < PFXBLK_) {
        // ----- prefix path: 16 q-rows amortize each K/V load -----
        const int idx   = blockIdx.x;
        const int n     = idx >> 8;           // /(H_*PCH_)
        const int h     = (idx >> 4) & 15;
        const int chunk = idx & 15;
        const int wv    = tid >> 6;           // wave 0..3
        const int lane  = tid & 63;
        const int r     = lane & 15;          // row = beam*2 + t
        const int c     = lane >> 4;          // dim quarter

        float qreg[16];
        const float* qbase = qT + (h * 64 + c * 16) * 64 + (n * 16 + r);
        #pragma unroll
        for (int u = 0; u < 16; u++) qreg[u] = qbase[u * 64] * QS_;

        const size_t pos0 = (size_t)(n * H_ + h) * S_ + chunk * PLEN_;
        const float* kb = pfx_k + pos0 * D_ + c * 16;
        const float* vb = pfx_v + pos0 * D_ + c * 16;
        const float* mrow = mask + (n * 8 + (r >> 1)) * TOT_ + chunk * PLEN_;

        float ctx[16];
        #pragma unroll
        for (int u = 0; u < 16; u++) ctx[u] = 0.f;
        float lsum = 0.f;

        #pragma unroll 2
        for (int i = 0; i < PLEN_ / 4; i++) {
            int p = i * 4 + wv;
            const float* kp = kb + p * D_;
            float4 k0 = *reinterpret_cast<const float4*>(kp + 0);
            float4 k1 = *reinterpret_cast<const float4*>(kp + 4);
            float4 k2 = *reinterpret_cast<const float4*>(kp + 8);
            float4 k3 = *reinterpret_cast<const float4*>(kp + 12);
            // 4 independent 4-FMA sub-chains, tree-combined
            float sA = qreg[0]*k0.x;  sA = fmaf(qreg[1],k0.y,sA);
            sA = fmaf(qreg[2],k0.z,sA); sA = fmaf(qreg[3],k0.w,sA);
            float sB = qreg[4]*k1.x;  sB = fmaf(qreg[5],k1.y,sB);
            sB = fmaf(qreg[6],k1.z,sB); sB = fmaf(qreg[7],k1.w,sB);
            float sC = qreg[8]*k2.x;  sC = fmaf(qreg[9],k2.y,sC);
            sC = fmaf(qreg[10],k2.z,sC); sC = fmaf(qreg[11],k2.w,sC);
            float sD = qreg[12]*k3.x; sD = fmaf(qreg[13],k3.y,sD);
            sD = fmaf(qreg[14],k3.z,sD); sD = fmaf(qreg[15],k3.w,sD);
            float s = (sA + sB) + (sC + sD);
            s += __shfl_xor(s, 16, 64);
            s += __shfl_xor(s, 32, 64);
            float e = exp2f(s + mrow[p] * LOG2E_);
            lsum += e;
            const float* vp = vb + p * D_;
            float4 v0 = *reinterpret_cast<const float4*>(vp + 0);
            float4 v1 = *reinterpret_cast<const float4*>(vp + 4);
            float4 v2 = *reinterpret_cast<const float4*>(vp + 8);
            float4 v3 = *reinterpret_cast<const float4*>(vp + 12);
            ctx[0]  += e * v0.x; ctx[1]  += e * v0.y; ctx[2]  += e * v0.z; ctx[3]  += e * v0.w;
            ctx[4]  += e * v1.x; ctx[5]  += e * v1.y; ctx[6]  += e * v1.z; ctx[7]  += e * v1.w;
            ctx[8]  += e * v2.x; ctx[9]  += e * v2.y; ctx[10] += e * v2.z; ctx[11] += e * v2.w;
            ctx[12] += e * v3.x; ctx[13] += e * v3.y; ctx[14] += e * v3.z; ctx[15] += e * v3.w;
        }

        const int base = wv * 1024 + r * 64 + c * 16;
        #pragma unroll
        for (int u = 0; u < 16; u += 4)
            *reinterpret_cast<float4*>(&sred[base + u]) =
                make_float4(ctx[u], ctx[u+1], ctx[u+2], ctx[u+3]);
        if (c == 0) sred[4096 + wv * 16 + r] = lsum;
        __syncthreads();

        const int pc = (n * H_ + h) * PCH_ + chunk;
        for (int e = tid; e < 1024; e += 256) {
            float s = sred[e] + sred[1024 + e] + sred[2048 + e] + sred[3072 + e];
            pfx_ctx[pc * 1024 + e] = s;   // e = r*64 + d
        }
        if (tid < 16) {
            float l = sred[4096 + tid] + sred[4096 + 16 + tid]
                    + sred[4096 + 32 + tid] + sred[4096 + 48 + tid];
            pfx_l[pc * 16 + tid] = l;
        }
    } else {
        // ----- cur path -----
        const int idx   = blockIdx.x - PFXBLK_;   // 0..4095
        const int b     = idx >> 3;               // nb*16+h
        const int chunk = idx & 7;
        const int nb    = b >> 4;
        const int h     = b & 15;
        const int g     = tid >> 4;     // group 0..15
        const int l16   = tid & 15;
        const int d0    = l16 * 4;

        float qf0[4], qf1[4];
        #pragma unroll
        for (int j = 0; j < 4; j++) {
            const float* qb = qT + (h * 64 + d0 + j) * 64 + nb * 2;
            qf0[j] = qb[0] * QS_;
            qf1[j] = qb[1] * QS_;
        }

        const float* pk_b = pk + ((nb * H_ + h) * (size_t)L_) * D_;
        const float* pv_b = pv + ((nb * H_ + h) * (size_t)L_) * D_;
        const float* mrow = mask + nb * TOT_ + S_;

        float l0 = 0.f, l1 = 0.f;
        float a0[4] = {0.f,0.f,0.f,0.f};
        float a1[4] = {0.f,0.f,0.f,0.f};

        const int p0 = chunk * CLEN_ + g;
        #pragma unroll 2
        for (int i = 0; i < CLEN_ / 16; i++) {
            int p = p0 + i * 16;                  // always < L_
            float4 kf = *reinterpret_cast<const float4*>(pk_b + p * D_ + d0);
            float s0 = fmaf(qf0[0],kf.x, qf0[1]*kf.y) + fmaf(qf0[2],kf.z, qf0[3]*kf.w);
            float s1 = fmaf(qf1[0],kf.x, qf1[1]*kf.y) + fmaf(qf1[2],kf.z, qf1[3]*kf.w);
            #pragma unroll
            for (int off = 1; off < 16; off <<= 1) {
                s0 += __shfl_xor(s0, off, 64);
                s1 += __shfl_xor(s1, off, 64);
            }
            float mC = mrow[p] * LOG2E_;
            float e0 = exp2f(s0 + mC);
            float e1 = exp2f(s1 + mC);
            l0 += e0; l1 += e1;
            float4 vf = *reinterpret_cast<const float4*>(pv_b + p * D_ + d0);
            a0[0] += e0 * vf.x; a0[1] += e0 * vf.y; a0[2] += e0 * vf.z; a0[3] += e0 * vf.w;
            a1[0] += e1 * vf.x; a1[1] += e1 * vf.y; a1[2] += e1 * vf.z; a1[3] += e1 * vf.w;
        }
        if (chunk == 7 && g < 2) {                // 2 new tokens
            const float* kn_b = knew + (nb * H_ + h) * (T_ * D_);
            const float* vn_b = vnew + (nb * H_ + h) * (T_ * D_);
            float4 kf = *reinterpret_cast<const float4*>(kn_b + g * D_ + d0);
            float s0 = fmaf(qf0[0],kf.x, qf0[1]*kf.y) + fmaf(qf0[2],kf.z, qf0[3]*kf.w);
            float s1 = fmaf(qf1[0],kf.x, qf1[1]*kf.y) + fmaf(qf1[2],kf.z, qf1[3]*kf.w);
            #pragma unroll
            for (int off = 1; off < 16; off <<= 1) {
                s0 += __shfl_xor(s0, off, 64);
                s1 += __shfl_xor(s1, off, 64);
            }
            float mC = mrow[L_ + g] * LOG2E_;
            float e0 = exp2f(s0 + mC);
            float e1 = exp2f(s1 + mC);
            l0 += e0; l1 += e1;
            float4 vf = *reinterpret_cast<const float4*>(vn_b + g * D_ + d0);
            a0[0] += e0 * vf.x; a0[1] += e0 * vf.y; a0[2] += e0 * vf.z; a0[3] += e0 * vf.w;
            a1[0] += e1 * vf.x; a1[1] += e1 * vf.y; a1[2] += e1 * vf.z; a1[3] += e1 * vf.w;
        }

        #pragma unroll
        for (int j = 0; j < 4; j++) {
            sred[g * 128 + d0 + j]      = a0[j];
            sred[g * 128 + 64 + d0 + j] = a1[j];
        }
        if (l16 == 0) { sred[2048 + g * 2] = l0; sred[2048 + g * 2 + 1] = l1; }
        __syncthreads();

        if (tid < 128) {
            int t = tid >> 6, d = tid & 63;
            float s = 0.f, l = 0.f;
            for (int g2 = 0; g2 < 16; g2++) {
                s += sred[g2 * 128 + t * 64 + d];
                l += sred[2048 + g2 * 2 + t];
            }
            const int cb = b * CCH_ + chunk;
            cur_ctx[(cb * 2 + t) * 64 + d] = s;
            if (d == 0) cur_l[cb * 2 + t] = l;
        }
    }
}

// ---------------------------------------------------------------------------
// Combine: out = (sum of 8 cur + 16 prefix ctx partials) / (sum of l partials)
// ---------------------------------------------------------------------------
__global__ __launch_bounds__(1024) void combine_kernel(
    const float* __restrict__ cur_ctx, const float* __restrict__ cur_l,
    const float* __restrict__ pfx_ctx, const float* __restrict__ pfx_l,
    float* __restrict__ out)
{
    const int row = blockIdx.x;           // nb*2+t
    const int nb  = row >> 1, t = row & 1;
    const int n   = nb >> 3;
    const int r   = (nb & 7) * 2 + t;
    const int tid = threadIdx.x;          // h*64+d
    const int h   = tid >> 6, d = tid & 63;
    const int b   = nb * 16 + h;

    float val = 0.f, l = 0.f;
    #pragma unroll
    for (int ch = 0; ch < CCH_; ch++) {
        int cb = b * CCH_ + ch;
        val += cur_ctx[(cb * 2 + t) * 64 + d];
        l   += cur_l[cb * 2 + t];
    }
    #pragma unroll
    for (int ch = 0; ch < PCH_; ch++) {
        int pc = (n * H_ + h) * PCH_ + ch;
        val += pfx_ctx[pc * 1024 + r * 64 + d];
        l   += pfx_l[pc * 16 + r];
    }
    out[row * 1024 + tid] = val / l;
}

extern "C" void kernel_launch(void* const* d_in, const int* in_sizes, int n_in,
                              void* d_out, int out_size, void* d_ws, size_t ws_size,
                              hipStream_t stream) {
    const float* hidden = (const float*)d_in[0];
    const float* mask   = (const float*)d_in[1];
    const float* pfxk   = (const float*)d_in[2];
    const float* pfxv   = (const float*)d_in[3];
    const float* pk     = (const float*)d_in[4];
    const float* pv     = (const float*)d_in[5];
    const float* Wq     = (const float*)d_in[6];
    const float* bq     = (const float*)d_in[7];
    const float* Wk     = (const float*)d_in[8];
    const float* bk     = (const float*)d_in[9];
    const float* Wv     = (const float*)d_in[10];
    const float* bv     = (const float*)d_in[11];

    float* qT      = (float*)d_ws;             // 65536
    float* knew    = qT + 65536;               // 65536
    float* vnew    = knew + 65536;             // 65536
    float* cur_ctx = vnew + 65536;             // 4096*2*64 = 524288
    float* cur_l   = cur_ctx + 524288;         // 8192
    float* pfx_ctx = cur_l + 8192;             // 1024*1024 = 1048576
    float* pfx_l   = pfx_ctx + 1048576;        // 16384

    qkv_kernel<<<192, 256, 0, stream>>>(hidden, Wq, bq, Wk, bk, Wv, bv,
                                        qT, knew, vnew);
    partial_kernel<<<PFXBLK_ + CURBLK_, 256, 0, stream>>>(
        mask, pfxk, pfxv, pk, pv, qT, knew, vnew,
        cur_ctx, cur_l, pfx_ctx, pfx_l);
    combine_kernel<<<64, 1024, 0, stream>>>(cur_ctx, cur_l, pfx_ctx, pfx_l,
                                            (float*)d_out);
}